// Round 4
// baseline (15193.764 us; speedup 1.0000x reference)
//
#include <hip/hip_runtime.h>
#include <cstdint>
#include <cstddef>

typedef unsigned short u16;
typedef short s8v __attribute__((ext_vector_type(8)));
typedef float f32x4 __attribute__((ext_vector_type(4)));
typedef u16 u16x4 __attribute__((ext_vector_type(4)));

#define DEV __device__ __forceinline__

DEV u16 f2bf(float f) {
  union { float f; uint32_t u; } a; a.f = f;
  uint32_t u = a.u;
  return (u16)((u + 0x7fffu + ((u >> 16) & 1u)) >> 16);
}
DEV float bf2f(u16 h) {
  union { uint32_t u; float f; } a; a.u = ((uint32_t)h) << 16;
  return a.f;
}
// split f32 into bf16 hi + bf16 lo (v ~= hi + lo, residual < 2^-16 rel)
DEV void f2bf_split(float v, u16& hi, u16& lo) {
  hi = f2bf(v);
  lo = f2bf(v - bf2f(hi));
}

// ---------------------------------------------------------------------------
// Weight transpose+cast: W[K,N] f32 -> WThi/WTlo[N,K] bf16 split.
// ---------------------------------------------------------------------------
__global__ __launch_bounds__(256) void k_transpose(const float* __restrict__ W,
                                                   u16* __restrict__ WThi,
                                                   u16* __restrict__ WTlo, int K, int N) {
  __shared__ float tile[32][33];
  int k0 = blockIdx.x * 32, n0 = blockIdx.y * 32;
  int tx = threadIdx.x & 31, ty = threadIdx.x >> 5;  // 32 x 8
#pragma unroll
  for (int i = 0; i < 32; i += 8)
    tile[ty + i][tx] = W[(size_t)(k0 + ty + i) * N + n0 + tx];
  __syncthreads();
#pragma unroll
  for (int i = 0; i < 32; i += 8) {
    float w = tile[tx][ty + i];
    u16 hi, lo; f2bf_split(w, hi, lo);
    size_t idx = (size_t)(n0 + ty + i) * K + k0 + tx;
    WThi[idx] = hi;
    WTlo[idx] = lo;
  }
}

// ---------------------------------------------------------------------------
// Embedding: x[row, c] = emb[tok][c] + pos[p][c]; writes f32 + hi/lo bf16.
// ---------------------------------------------------------------------------
__global__ __launch_bounds__(256) void k_embed(const int* __restrict__ fen,
                                               const int* __restrict__ uci,
                                               const float* __restrict__ femb,
                                               const float* __restrict__ uemb,
                                               const float* __restrict__ pemb,
                                               float* __restrict__ xf,
                                               u16* __restrict__ xhi, u16* __restrict__ xlo,
                                               int b0) {
  int row = blockIdx.x;
  int c = threadIdx.x;
  int bl = row / 78, p = row % 78;
  int b = b0 + bl;
  int tok;
  const float* e;
  if (p < 77) { tok = fen[b * 77 + p]; e = femb; }
  else        { tok = uci[b];          e = uemb; }
  float v = e[(size_t)tok * 256 + c] + pemb[p * 256 + c];
  size_t idx = (size_t)row * 256 + c;
  xf[idx] = v;
  u16 hi, lo; f2bf_split(v, hi, lo);
  xhi[idx] = hi;
  xlo[idx] = lo;
}

// ---------------------------------------------------------------------------
// Split-bf16 MFMA GEMM, MERGED: C = (Ahi+Alo)(Bhi+Blo)^T via hi*hi + hi*lo +
// lo*hi accumulated in ONE k-loop traversal (r3 ran 3 sequential sweeps:
// 3x staging, 3x barriers). 4 LDS tiles (73.7 KB -> 2 blocks/CU), 128x128
// tile, 4 waves (2x2), 16x16x32 bf16 MFMA, fp32 accumulate.
// LDS rows padded +8 bf16 (144 B stride, 16B-aligned) -> 2-way bank alias
// (free, m136). Per k-tile per wave: 32 ds_read_b128, 96 MFMA (~balanced).
// ---------------------------------------------------------------------------
template <bool RELU, bool OUT_F32, bool OUT_SPLIT>
__global__ __launch_bounds__(256) void k_gemm(const u16* __restrict__ Ahi,
                                              const u16* __restrict__ Alo,
                                              const u16* __restrict__ Bhi,
                                              const u16* __restrict__ Blo,
                                              const float* __restrict__ bias,
                                              float* __restrict__ Cf,
                                              u16* __restrict__ Chi, u16* __restrict__ Clo,
                                              int M, int N, int K) {
  __shared__ __align__(16) u16 Ah[128][72];
  __shared__ __align__(16) u16 Al[128][72];
  __shared__ __align__(16) u16 Bh[128][72];
  __shared__ __align__(16) u16 Bl[128][72];
  const int tid = threadIdx.x;
  const int wid = tid >> 6, lane = tid & 63;
  const int wr = wid >> 1, wc = wid & 1;          // 2x2 waves, each 64x64
  const int m0 = blockIdx.x * 128, n0 = blockIdx.y * 128;
  f32x4 acc[4][4] = {};
  const int sr = tid >> 3;                        // staging row 0..31
  const int sc = (tid & 7) * 8;                   // staging col 0..56

  for (int kt = 0; kt < K; kt += 64) {
#pragma unroll
    for (int i = 0; i < 4; i++) {
      int row = sr + i * 32;
      size_t ga = (size_t)(m0 + row) * K + kt + sc;
      size_t gb = (size_t)(n0 + row) * K + kt + sc;
      *(s8v*)&Ah[row][sc] = *(const s8v*)&Ahi[ga];
      *(s8v*)&Al[row][sc] = *(const s8v*)&Alo[ga];
      *(s8v*)&Bh[row][sc] = *(const s8v*)&Bhi[gb];
      *(s8v*)&Bl[row][sc] = *(const s8v*)&Blo[gb];
    }
    __syncthreads();
#pragma unroll
    for (int kk = 0; kk < 2; kk++) {
      s8v ah[4], al[4], bh[4], bl[4];
      const int fr = lane & 15, fc = kk * 32 + (lane >> 4) * 8;
#pragma unroll
      for (int i = 0; i < 4; i++) {
        ah[i] = *(const s8v*)&Ah[wr * 64 + i * 16 + fr][fc];
        al[i] = *(const s8v*)&Al[wr * 64 + i * 16 + fr][fc];
        bh[i] = *(const s8v*)&Bh[wc * 64 + i * 16 + fr][fc];
        bl[i] = *(const s8v*)&Bl[wc * 64 + i * 16 + fr][fc];
      }
#pragma unroll
      for (int i = 0; i < 4; i++)
#pragma unroll
        for (int j = 0; j < 4; j++) {
          acc[i][j] = __builtin_amdgcn_mfma_f32_16x16x32_bf16(ah[i], bh[j], acc[i][j], 0, 0, 0);
          acc[i][j] = __builtin_amdgcn_mfma_f32_16x16x32_bf16(ah[i], bl[j], acc[i][j], 0, 0, 0);
          acc[i][j] = __builtin_amdgcn_mfma_f32_16x16x32_bf16(al[i], bh[j], acc[i][j], 0, 0, 0);
        }
    }
    __syncthreads();
  }
  // Epilogue. C/D layout (m89/m91): col = lane&15, row = (lane>>4)*4 + r.
#pragma unroll
  for (int j = 0; j < 4; j++) {
    int col = n0 + wc * 64 + j * 16 + (lane & 15);
    float bv = bias[col];
#pragma unroll
    for (int i = 0; i < 4; i++) {
#pragma unroll
      for (int r = 0; r < 4; r++) {
        int row = m0 + wr * 64 + i * 16 + (lane >> 4) * 4 + r;
        float v = acc[i][j][r] + bv;
        if (RELU) v = fmaxf(v, 0.f);
        size_t idx = (size_t)row * N + col;
        if (OUT_F32) Cf[idx] = v;
        if (OUT_SPLIT) {
          u16 hi, lo; f2bf_split(v, hi, lo);
          Chi[idx] = hi;
          Clo[idx] = lo;
        }
      }
    }
  }
}

// ---------------------------------------------------------------------------
// Attention: one block (128 thr) per (batch-elem, head). 78x78 scores, fp32.
// Reads fp32 qkv; writes o as hi/lo bf16 split. Ss has +1 col pad.
// ---------------------------------------------------------------------------
__global__ __launch_bounds__(128) void k_attn(const float* __restrict__ qkvf,
                                              u16* __restrict__ ohi, u16* __restrict__ olo) {
  __shared__ float Ks[78][68];   // 68-f32 stride: 16B-aligned rows, 2-way banks
  __shared__ float Vs[78][68];
  __shared__ float Ss[78][79];
  const int bl = blockIdx.x >> 2, h = blockIdx.x & 3;
  const int tid = threadIdx.x;
  const size_t rowbase = (size_t)bl * 78;
  for (int ci = tid; ci < 1248; ci += 128) {   // 78 rows * 16 float4 chunks
    int row = ci >> 4, c4 = (ci & 15) * 4;
    const float* kp = &qkvf[(rowbase + row) * 768 + 256 + h * 64 + c4];
    *(float4*)&Ks[row][c4] = *(const float4*)kp;
    *(float4*)&Vs[row][c4] = *(const float4*)(kp + 256);
  }
  __syncthreads();
  const int q = tid;
  if (q < 78) {
    float qv[64];
    const float* qp = &qkvf[(rowbase + q) * 768 + h * 64];
#pragma unroll
    for (int d4 = 0; d4 < 64; d4 += 4) {
      float4 t = *(const float4*)&qp[d4];
      qv[d4] = t.x; qv[d4 + 1] = t.y; qv[d4 + 2] = t.z; qv[d4 + 3] = t.w;
    }
    float mx = -1e30f;
    for (int k = 0; k < 78; k++) {
      float s = 0.f;
#pragma unroll
      for (int d = 0; d < 64; d++) s += qv[d] * Ks[k][d];
      s *= 0.125f;                      // 1/sqrt(64)
      Ss[q][k] = s;
      mx = fmaxf(mx, s);
    }
    float sum = 0.f;
    for (int k = 0; k < 78; k++) { float e = __expf(Ss[q][k] - mx); Ss[q][k] = e; sum += e; }
    float inv = 1.f / sum;
    float ov[64];
#pragma unroll
    for (int d = 0; d < 64; d++) ov[d] = 0.f;
    for (int k = 0; k < 78; k++) {
      float p = Ss[q][k];
#pragma unroll
      for (int d = 0; d < 64; d++) ov[d] += p * Vs[k][d];
    }
    size_t obase = (rowbase + q) * 256 + h * 64;
#pragma unroll
    for (int d8 = 0; d8 < 64; d8 += 8) {
      s8v whi, wlo;
#pragma unroll
      for (int j = 0; j < 8; j++) {
        u16 hi, lo; f2bf_split(ov[d8 + j] * inv, hi, lo);
        whi[j] = (short)hi; wlo[j] = (short)lo;
      }
      *(s8v*)&ohi[obase + d8] = whi;
      *(s8v*)&olo[obase + d8] = wlo;
    }
  }
}

// ---------------------------------------------------------------------------
// (opt add) + LayerNorm over D=256. 4 rows/block, one wave per row.
// Writes f32 + hi/lo bf16.
// ---------------------------------------------------------------------------
template <bool ADD>
__global__ __launch_bounds__(256) void k_addln(const float* __restrict__ x,
                                               const float* __restrict__ t,
                                               const float* __restrict__ g,
                                               const float* __restrict__ b,
                                               float* __restrict__ xo,
                                               u16* __restrict__ xhi, u16* __restrict__ xlo) {
  int row = blockIdx.x * 4 + (threadIdx.x >> 6);
  int lane = threadIdx.x & 63;
  const float* xr = x + (size_t)row * 256;
  float4 v = *(const float4*)&xr[lane * 4];
  if (ADD) {
    float4 tv = *(const float4*)&t[(size_t)row * 256 + lane * 4];
    v.x += tv.x; v.y += tv.y; v.z += tv.z; v.w += tv.w;
  }
  float s = v.x + v.y + v.z + v.w;
  float q = v.x * v.x + v.y * v.y + v.z * v.z + v.w * v.w;
#pragma unroll
  for (int off = 32; off; off >>= 1) { s += __shfl_down(s, off); q += __shfl_down(q, off); }
  s = __shfl(s, 0); q = __shfl(q, 0);
  float mean = s * (1.f / 256.f);
  float var = q * (1.f / 256.f) - mean * mean;
  float rstd = rsqrtf(var + 1e-5f);
  float4 gg = *(const float4*)&g[lane * 4];
  float4 bb = *(const float4*)&b[lane * 4];
  float o0 = (v.x - mean) * rstd * gg.x + bb.x;
  float o1 = (v.y - mean) * rstd * gg.y + bb.y;
  float o2 = (v.z - mean) * rstd * gg.z + bb.z;
  float o3 = (v.w - mean) * rstd * gg.w + bb.w;
  size_t base = (size_t)row * 256 + lane * 4;
  *(float4*)&xo[base] = make_float4(o0, o1, o2, o3);
  u16 h0, l0, h1, l1, h2, l2, h3, l3;
  f2bf_split(o0, h0, l0); f2bf_split(o1, h1, l1);
  f2bf_split(o2, h2, l2); f2bf_split(o3, h3, l3);
  u16x4 vh = { h0, h1, h2, h3 };
  u16x4 vl = { l0, l1, l2, l3 };
  *(u16x4*)&xhi[base] = vh;
  *(u16x4*)&xlo[base] = vl;
}

// Mean over 78 tokens -> out[b, d]
__global__ __launch_bounds__(256) void k_mean(const float* __restrict__ p2,
                                              float* __restrict__ out, int b0) {
  int bl = blockIdx.x, d = threadIdx.x;
  const float* base = p2 + (size_t)bl * 78 * 256 + d;
  float s = 0.f;
#pragma unroll 13
  for (int p = 0; p < 78; p++) s += base[(size_t)p * 256];
  out[(size_t)(b0 + bl) * 256 + d] = s * (1.f / 78.f);
}

__global__ __launch_bounds__(256) void k_zero(float* p, int n) {
  int i = blockIdx.x * 256 + threadIdx.x;
  if (i < n) p[i] = 0.f;
}

// ---------------------------------------------------------------------------
// HRM (fp32). concat order: [zL, zH, out] for l_net, [zH, zL] for h_net.
// baseL = L_b1 + zH@L_w1[256:512] + out@L_w1[512:768] (recomputed per period)
// ---------------------------------------------------------------------------
__global__ __launch_bounds__(256) void k_lbase(const float* __restrict__ zH,
                                               const float* __restrict__ out,
                                               const float* __restrict__ W1,
                                               const float* __restrict__ b1,
                                               float* __restrict__ baseL) {
  int r0 = blockIdx.x * 4, col = threadIdx.x;
  __shared__ float t[4][512];
#pragma unroll
  for (int i = 0; i < 4; i++) {
    t[i][col] = zH[(size_t)(r0 + i) * 256 + col];
    t[i][256 + col] = out[(size_t)(r0 + i) * 256 + col];
  }
  __syncthreads();
  float acc[4];
#pragma unroll
  for (int i = 0; i < 4; i++) acc[i] = b1[col];
  for (int k = 0; k < 512; k++) {
    float w = W1[(size_t)(256 + k) * 256 + col];
#pragma unroll
    for (int i = 0; i < 4; i++) acc[i] += t[i][k] * w;
  }
#pragma unroll
  for (int i = 0; i < 4; i++) baseL[(size_t)(r0 + i) * 256 + col] = acc[i];
}

DEV void row_ln_stats(float a2[4], int col, float (*redS)[4], float (*redQ)[4],
                      float mean[4], float rstd[4]) {
  int wid = col >> 6, lane = col & 63;
#pragma unroll
  for (int i = 0; i < 4; i++) {
    float s = a2[i], q = a2[i] * a2[i];
#pragma unroll
    for (int off = 32; off; off >>= 1) { s += __shfl_down(s, off); q += __shfl_down(q, off); }
    if (lane == 0) { redS[i][wid] = s; redQ[i][wid] = q; }
  }
  __syncthreads();
#pragma unroll
  for (int i = 0; i < 4; i++) {
    float s = redS[i][0] + redS[i][1] + redS[i][2] + redS[i][3];
    float q = redQ[i][0] + redQ[i][1] + redQ[i][2] + redQ[i][3];
    mean[i] = s * (1.f / 256.f);
    float var = q * (1.f / 256.f) - mean[i] * mean[i];
    rstd[i] = rsqrtf(var + 1e-5f);
  }
}

__global__ __launch_bounds__(256) void k_lstep(float* __restrict__ zL,
                                               const float* __restrict__ baseL,
                                               const float* __restrict__ W1,
                                               const float* __restrict__ W2,
                                               const float* __restrict__ b2,
                                               const float* __restrict__ g,
                                               const float* __restrict__ bb) {
  int r0 = blockIdx.x * 4, col = threadIdx.x;
  __shared__ float t[4][256];
  __shared__ float h1[4][256];
  __shared__ float redS[4][4], redQ[4][4];
#pragma unroll
  for (int i = 0; i < 4; i++) t[i][col] = zL[(size_t)(r0 + i) * 256 + col];
  __syncthreads();
  float acc[4];
#pragma unroll
  for (int i = 0; i < 4; i++) acc[i] = baseL[(size_t)(r0 + i) * 256 + col];
  for (int k = 0; k < 256; k++) {
    float w = W1[(size_t)k * 256 + col];
#pragma unroll
    for (int i = 0; i < 4; i++) acc[i] += t[i][k] * w;
  }
#pragma unroll
  for (int i = 0; i < 4; i++) h1[i][col] = fmaxf(acc[i], 0.f);
  __syncthreads();
  float a2[4];
#pragma unroll
  for (int i = 0; i < 4; i++) a2[i] = b2[col];
  for (int k = 0; k < 256; k++) {
    float w = W2[(size_t)k * 256 + col];
#pragma unroll
    for (int i = 0; i < 4; i++) a2[i] += h1[i][k] * w;
  }
#pragma unroll
  for (int i = 0; i < 4; i++) a2[i] = fmaxf(a2[i], 0.f);
  float mean[4], rstd[4];
  row_ln_stats(a2, col, redS, redQ, mean, rstd);
#pragma unroll
  for (int i = 0; i < 4; i++)
    zL[(size_t)(r0 + i) * 256 + col] = (a2[i] - mean[i]) * rstd[i] * g[col] + bb[col];
}

__global__ __launch_bounds__(256) void k_hstep(float* __restrict__ zH,
                                               const float* __restrict__ zL,
                                               const float* __restrict__ W1,
                                               const float* __restrict__ b1,
                                               const float* __restrict__ W2,
                                               const float* __restrict__ b2,
                                               const float* __restrict__ g,
                                               const float* __restrict__ bb) {
  int r0 = blockIdx.x * 4, col = threadIdx.x;
  __shared__ float t[4][512];
  __shared__ float h1[4][256];
  __shared__ float redS[4][4], redQ[4][4];
#pragma unroll
  for (int i = 0; i < 4; i++) {
    t[i][col] = zH[(size_t)(r0 + i) * 256 + col];
    t[i][256 + col] = zL[(size_t)(r0 + i) * 256 + col];
  }
  __syncthreads();
  float acc[4];
#pragma unroll
  for (int i = 0; i < 4; i++) acc[i] = b1[col];
  for (int k = 0; k < 512; k++) {
    float w = W1[(size_t)k * 256 + col];
#pragma unroll
    for (int i = 0; i < 4; i++) acc[i] += t[i][k] * w;
  }
#pragma unroll
  for (int i = 0; i < 4; i++) h1[i][col] = fmaxf(acc[i], 0.f);
  __syncthreads();
  float a2[4];
#pragma unroll
  for (int i = 0; i < 4; i++) a2[i] = b2[col];
  for (int k = 0; k < 256; k++) {
    float w = W2[(size_t)k * 256 + col];
#pragma unroll
    for (int i = 0; i < 4; i++) a2[i] += h1[i][k] * w;
  }
#pragma unroll
  for (int i = 0; i < 4; i++) a2[i] = fmaxf(a2[i], 0.f);
  float mean[4], rstd[4];
  row_ln_stats(a2, col, redS, redQ, mean, rstd);
#pragma unroll
  for (int i = 0; i < 4; i++)
    zH[(size_t)(r0 + i) * 256 + col] = (a2[i] - mean[i]) * rstd[i] * g[col] + bb[col];
}

// Final head: vh = LN(zH); y = relu(vh @ vw1 + vb1) @ vw2 + vb2  -> [1024,128]
__global__ __launch_bounds__(256) void k_vh(const float* __restrict__ zH,
                                            const float* __restrict__ g,
                                            const float* __restrict__ bb,
                                            const float* __restrict__ W1,
                                            const float* __restrict__ b1,
                                            const float* __restrict__ W2,
                                            const float* __restrict__ b2,
                                            float* __restrict__ out) {
  int r0 = blockIdx.x * 4, col = threadIdx.x;
  __shared__ float t[4][256];
  __shared__ float h1[4][256];
  __shared__ float redS[4][4], redQ[4][4];
  float v[4];
#pragma unroll
  for (int i = 0; i < 4; i++) v[i] = zH[(size_t)(r0 + i) * 256 + col];
  float mean[4], rstd[4];
  row_ln_stats(v, col, redS, redQ, mean, rstd);
#pragma unroll
  for (int i = 0; i < 4; i++) t[i][col] = (v[i] - mean[i]) * rstd[i] * g[col] + bb[col];
  __syncthreads();
  float acc[4];
#pragma unroll
  for (int i = 0; i < 4; i++) acc[i] = b1[col];
  for (int k = 0; k < 256; k++) {
    float w = W1[(size_t)k * 256 + col];
#pragma unroll
    for (int i = 0; i < 4; i++) acc[i] += t[i][k] * w;
  }
#pragma unroll
  for (int i = 0; i < 4; i++) h1[i][col] = fmaxf(acc[i], 0.f);
  __syncthreads();
  if (col < 128) {
    float a2[4];
#pragma unroll
    for (int i = 0; i < 4; i++) a2[i] = b2[col];
    for (int k = 0; k < 256; k++) {
      float w = W2[(size_t)k * 128 + col];
#pragma unroll
      for (int i = 0; i < 4; i++) a2[i] += h1[i][k] * w;
    }
#pragma unroll
    for (int i = 0; i < 4; i++) out[(size_t)(r0 + i) * 128 + col] = a2[i];
  }
}

// ---------------------------------------------------------------------------
extern "C" void kernel_launch(void* const* d_in, const int* in_sizes, int n_in,
                              void* d_out, int out_size, void* d_ws, size_t ws_size,
                              hipStream_t stream) {
  (void)in_sizes; (void)n_in; (void)out_size;
  const int* fen = (const int*)d_in[0];
  const int* uci = (const int*)d_in[1];
  const float* femb = (const float*)d_in[2];
  const float* uemb = (const float*)d_in[3];
  const float* pemb = (const float*)d_in[4];
  const float* wqkv = (const float*)d_in[5];
  const float* bqkv = (const float*)d_in[6];
  const float* wo_ = (const float*)d_in[7];
  const float* bo_ = (const float*)d_in[8];
  const float* ln1g = (const float*)d_in[9];
  const float* ln1b = (const float*)d_in[10];
  const float* w1_ = (const float*)d_in[11];
  const float* b1_ = (const float*)d_in[12];
  const float* w2_ = (const float*)d_in[13];
  const float* b2_ = (const float*)d_in[14];
  const float* ln2g = (const float*)d_in[15];
  const float* ln2b = (const float*)d_in[16];
  const float* postg = (const float*)d_in[17];
  const float* postb = (const float*)d_in[18];
  const float* pw1 = (const float*)d_in[19];
  const float* pb1 = (const float*)d_in[20];
  const float* pw2 = (const float*)d_in[21];
  const float* pb2 = (const float*)d_in[22];
  const float* Lw1 = (const float*)d_in[23];
  const float* Lb1 = (const float*)d_in[24];
  const float* Lw2 = (const float*)d_in[25];
  const float* Lb2 = (const float*)d_in[26];
  const float* Llng = (const float*)d_in[27];
  const float* Llnb = (const float*)d_in[28];
  const float* Hw1 = (const float*)d_in[29];
  const float* Hb1 = (const float*)d_in[30];
  const float* Hw2 = (const float*)d_in[31];
  const float* Hb2 = (const float*)d_in[32];
  const float* Hlng = (const float*)d_in[33];
  const float* Hlnb = (const float*)d_in[34];
  const float* vhg = (const float*)d_in[35];
  const float* vhb = (const float*)d_in[36];
  const float* vw1 = (const float*)d_in[37];
  const float* vb1 = (const float*)d_in[38];
  const float* vw2 = (const float*)d_in[39];
  const float* vb2 = (const float*)d_in[40];

  // ---- workspace carve-up ----
  char* p = (char*)d_ws;
  auto alloc = [&](size_t bytes) -> void* {
    void* r = (void*)p;
    p += (bytes + 255) & ~(size_t)255;
    return r;
  };
  float* outf = (float*)alloc(1024 * 256 * 4);       // pooled "out" [1024,256]
  float* baseL = (float*)alloc(1024 * 256 * 4);
  float* zLH = (float*)alloc(2 * 1024 * 256 * 4);
  float* zL = zLH;
  float* zH = zLH + 1024 * 256;
  u16* wqThi = (u16*)alloc((size_t)4 * 768 * 256 * 2);
  u16* wqTlo = (u16*)alloc((size_t)4 * 768 * 256 * 2);
  u16* woThi = (u16*)alloc((size_t)4 * 256 * 256 * 2);
  u16* woTlo = (u16*)alloc((size_t)4 * 256 * 256 * 2);
  u16* w1Thi = (u16*)alloc((size_t)4 * 2048 * 256 * 2);
  u16* w1Tlo = (u16*)alloc((size_t)4 * 2048 * 256 * 2);
  u16* w2Thi = (u16*)alloc((size_t)4 * 256 * 2048 * 2);
  u16* w2Tlo = (u16*)alloc((size_t)4 * 256 * 2048 * 2);
  u16* pw1Thi = (u16*)alloc((size_t)256 * 256 * 2);
  u16* pw1Tlo = (u16*)alloc((size_t)256 * 256 * 2);
  u16* pw2Thi = (u16*)alloc((size_t)256 * 256 * 2);
  u16* pw2Tlo = (u16*)alloc((size_t)256 * 256 * 2);

  size_t fixed = (size_t)(p - (char*)d_ws);
  // per-row chunk bytes: xf 1024 + tmp 1024 + xhi/xlo 1024 + qkvf 3072
  //                    + ohi/olo 1024 + hhi/hlo 8192 = 15360
  // Prefer the LARGEST chunk that fits (descending memory need): bigger M
  // per GEMM -> bigger grids (ffn1 at NC=1: 624x16 blocks), ~5x fewer
  // launches than NC=8. (r3 had this list mis-ordered -> ran NC=8/16.)
  int NC = 16;
  for (int c : {1, 2, 4, 8, 16}) {
    size_t Mc_ = (size_t)(1024 / c) * 78;
    if (fixed + Mc_ * 15360 + (size_t)(1 << 20) <= ws_size) { NC = c; break; }
  }
  const int Bc = 1024 / NC;
  const size_t Mc = (size_t)Bc * 78;

  float* xf = (float*)alloc(Mc * 256 * 4);
  float* tmp = (float*)alloc(Mc * 256 * 4);
  u16* xhi = (u16*)alloc(Mc * 256 * 2);
  u16* xlo = (u16*)alloc(Mc * 256 * 2);
  float* qkvf = (float*)alloc(Mc * 768 * 4);
  u16* ohi = (u16*)alloc(Mc * 256 * 2);   // attn out; reused as pool1 out
  u16* olo = (u16*)alloc(Mc * 256 * 2);
  u16* hhi = (u16*)alloc(Mc * 2048 * 2);
  u16* hlo = (u16*)alloc(Mc * 2048 * 2);

  // ---- weight transpose+split (per call; inputs restored each launch) ----
  auto tr = [&](const float* W, u16* WThi, u16* WTlo, int K, int N) {
    k_transpose<<<dim3(K / 32, N / 32), 256, 0, stream>>>(W, WThi, WTlo, K, N);
  };
  for (int l = 0; l < 4; l++) {
    tr(wqkv + (size_t)l * 256 * 768, wqThi + (size_t)l * 768 * 256,
       wqTlo + (size_t)l * 768 * 256, 256, 768);
    tr(wo_ + (size_t)l * 256 * 256, woThi + (size_t)l * 256 * 256,
       woTlo + (size_t)l * 256 * 256, 256, 256);
    tr(w1_ + (size_t)l * 256 * 2048, w1Thi + (size_t)l * 2048 * 256,
       w1Tlo + (size_t)l * 2048 * 256, 256, 2048);
    tr(w2_ + (size_t)l * 2048 * 256, w2Thi + (size_t)l * 256 * 2048,
       w2Tlo + (size_t)l * 256 * 2048, 2048, 256);
  }
  tr(pw1, pw1Thi, pw1Tlo, 256, 256);
  tr(pw2, pw2Thi, pw2Tlo, 256, 256);

  // ---- transformer + pool, chunked over batch ----
  const int MT = (int)(Mc / 128);
  for (int ch = 0; ch < NC; ch++) {
    int b0 = ch * Bc;
    k_embed<<<(int)Mc, 256, 0, stream>>>(fen, uci, femb, uemb, pemb, xf, xhi, xlo, b0);
    for (int l = 0; l < 4; l++) {
      k_gemm<false, true, false><<<dim3(MT, 6), 256, 0, stream>>>(
          xhi, xlo, wqThi + (size_t)l * 768 * 256, wqTlo + (size_t)l * 768 * 256,
          bqkv + l * 768, qkvf, nullptr, nullptr, (int)Mc, 768, 256);
      k_attn<<<Bc * 4, 128, 0, stream>>>(qkvf, ohi, olo);
      k_gemm<false, true, false><<<dim3(MT, 2), 256, 0, stream>>>(
          ohi, olo, woThi + (size_t)l * 256 * 256, woTlo + (size_t)l * 256 * 256,
          bo_ + l * 256, tmp, nullptr, nullptr, (int)Mc, 256, 256);
      k_addln<true><<<(int)(Mc / 4), 256, 0, stream>>>(
          xf, tmp, ln1g + l * 256, ln1b + l * 256, xf, xhi, xlo);
      k_gemm<true, false, true><<<dim3(MT, 16), 256, 0, stream>>>(
          xhi, xlo, w1Thi + (size_t)l * 2048 * 256, w1Tlo + (size_t)l * 2048 * 256,
          b1_ + l * 2048, nullptr, hhi, hlo, (int)Mc, 2048, 256);
      k_gemm<false, true, false><<<dim3(MT, 2), 256, 0, stream>>>(
          hhi, hlo, w2Thi + (size_t)l * 256 * 2048, w2Tlo + (size_t)l * 256 * 2048,
          b2_ + l * 256, tmp, nullptr, nullptr, (int)Mc, 256, 2048);
      k_addln<true><<<(int)(Mc / 4), 256, 0, stream>>>(
          xf, tmp, ln2g + l * 256, ln2b + l * 256, xf, xhi, xlo);
    }
    k_addln<false><<<(int)(Mc / 4), 256, 0, stream>>>(xf, nullptr, postg, postb, xf, xhi, xlo);
    k_gemm<true, false, true><<<dim3(MT, 2), 256, 0, stream>>>(
        xhi, xlo, pw1Thi, pw1Tlo, pb1, nullptr, ohi, olo, (int)Mc, 256, 256);
    k_gemm<true, true, false><<<dim3(MT, 2), 256, 0, stream>>>(
        ohi, olo, pw2Thi, pw2Tlo, pb2, tmp, nullptr, nullptr, (int)Mc, 256, 256);
    k_mean<<<Bc, 256, 0, stream>>>(tmp, outf, b0);
  }

  // ---- HRM recurrence (fp32) ----
  k_zero<<<(2 * 1024 * 256) / 256, 256, 0, stream>>>(zLH, 2 * 1024 * 256);
  for (int st = 0; st < 64; st++) {
    if ((st & 7) == 0)
      k_lbase<<<256, 256, 0, stream>>>(zH, outf, Lw1, Lb1, baseL);
    k_lstep<<<256, 256, 0, stream>>>(zL, baseL, Lw1, Lw2, Lb2, Llng, Llnb);
    if ((st & 7) == 7)
      k_hstep<<<256, 256, 0, stream>>>(zH, zL, Hw1, Hb1, Hw2, Hb2, Hlng, Hlnb);
  }
  k_vh<<<256, 256, 0, stream>>>(zH, vhg, vhb, vw1, vb1, vw2, vb2, (float*)d_out);
}

// Round 6
// 10046.926 us; speedup vs baseline: 1.5123x; 1.5123x over previous
//
#include <hip/hip_runtime.h>
#include <cstdint>
#include <cstddef>

typedef unsigned short u16;
typedef short s8v __attribute__((ext_vector_type(8)));
typedef float f32x4 __attribute__((ext_vector_type(4)));
typedef u16 u16x4 __attribute__((ext_vector_type(4)));

#define DEV __device__ __forceinline__

DEV u16 f2bf(float f) {
  union { float f; uint32_t u; } a; a.f = f;
  uint32_t u = a.u;
  return (u16)((u + 0x7fffu + ((u >> 16) & 1u)) >> 16);
}
DEV float bf2f(u16 h) {
  union { uint32_t u; float f; } a; a.u = ((uint32_t)h) << 16;
  return a.f;
}
// split f32 into bf16 hi + bf16 lo (v ~= hi + lo, residual < 2^-16 rel)
DEV void f2bf_split(float v, u16& hi, u16& lo) {
  hi = f2bf(v);
  lo = f2bf(v - bf2f(hi));
}

// ---------------------------------------------------------------------------
// Weight transpose+cast: W[K,N] f32 -> WThi/WTlo[N,K] bf16 split.
// ---------------------------------------------------------------------------
__global__ __launch_bounds__(256) void k_transpose(const float* __restrict__ W,
                                                   u16* __restrict__ WThi,
                                                   u16* __restrict__ WTlo, int K, int N) {
  __shared__ float tile[32][33];
  int k0 = blockIdx.x * 32, n0 = blockIdx.y * 32;
  int tx = threadIdx.x & 31, ty = threadIdx.x >> 5;  // 32 x 8
#pragma unroll
  for (int i = 0; i < 32; i += 8)
    tile[ty + i][tx] = W[(size_t)(k0 + ty + i) * N + n0 + tx];
  __syncthreads();
#pragma unroll
  for (int i = 0; i < 32; i += 8) {
    float w = tile[tx][ty + i];
    u16 hi, lo; f2bf_split(w, hi, lo);
    size_t idx = (size_t)(n0 + ty + i) * K + k0 + tx;
    WThi[idx] = hi;
    WTlo[idx] = lo;
  }
}

// ---------------------------------------------------------------------------
// Embedding: x[row, c] = emb[tok][c] + pos[p][c]; writes f32 + hi/lo bf16.
// ---------------------------------------------------------------------------
__global__ __launch_bounds__(256) void k_embed(const int* __restrict__ fen,
                                               const int* __restrict__ uci,
                                               const float* __restrict__ femb,
                                               const float* __restrict__ uemb,
                                               const float* __restrict__ pemb,
                                               float* __restrict__ xf,
                                               u16* __restrict__ xhi, u16* __restrict__ xlo,
                                               int b0) {
  int row = blockIdx.x;
  int c = threadIdx.x;
  int bl = row / 78, p = row % 78;
  int b = b0 + bl;
  int tok;
  const float* e;
  if (p < 77) { tok = fen[b * 77 + p]; e = femb; }
  else        { tok = uci[b];          e = uemb; }
  float v = e[(size_t)tok * 256 + c] + pemb[p * 256 + c];
  size_t idx = (size_t)row * 256 + c;
  xf[idx] = v;
  u16 hi, lo; f2bf_split(v, hi, lo);
  xhi[idx] = hi;
  xlo[idx] = lo;
}

// ---------------------------------------------------------------------------
// Split-bf16 MFMA GEMM, merged one-pass k-loop, BK=32.
// C = (Ahi+Alo)(Bhi+Blo)^T via hi*hi + hi*lo + lo*hi per k-tile.
// r4 lesson: BK=64 merged needed 73.7 KB LDS -> 2 blocks/CU -> regressed.
// BK=32: 4 tiles of [128][40] u16 = 40.96 KB -> LDS allows 4 blocks/CU
// (VGPR ~3); per 32-K per wave: 16 ds_read_b128 + 48 MFMA + 2 barriers,
// strictly cheaper than the r3 3-sweep at equal occupancy.
// [128][40]: row stride 20 dwords -> b128 reads spread uniformly 8/bank.
// B-fragments are the only long-lived frags (32 VGPRs); A streams (8).
// ---------------------------------------------------------------------------
template <bool RELU, bool OUT_F32, bool OUT_SPLIT>
__global__ __launch_bounds__(256) void k_gemm(const u16* __restrict__ Ahi,
                                              const u16* __restrict__ Alo,
                                              const u16* __restrict__ Bhi,
                                              const u16* __restrict__ Blo,
                                              const float* __restrict__ bias,
                                              float* __restrict__ Cf,
                                              u16* __restrict__ Chi, u16* __restrict__ Clo,
                                              int M, int N, int K) {
  __shared__ __align__(16) u16 Ah[128][40];
  __shared__ __align__(16) u16 Al[128][40];
  __shared__ __align__(16) u16 Bh[128][40];
  __shared__ __align__(16) u16 Bl[128][40];
  const int tid = threadIdx.x;
  const int wid = tid >> 6, lane = tid & 63;
  const int wr = wid >> 1, wc = wid & 1;          // 2x2 waves, each 64x64
  const int m0 = blockIdx.x * 128, n0 = blockIdx.y * 128;
  f32x4 acc[4][4] = {};
  const int sr = tid >> 2;                        // staging row 0..63
  const int sc = (tid & 3) * 8;                   // staging col 0,8,16,24

  for (int kt = 0; kt < K; kt += 32) {
#pragma unroll
    for (int i = 0; i < 2; i++) {
      int row = sr + i * 64;
      size_t ga = (size_t)(m0 + row) * K + kt + sc;
      size_t gb = (size_t)(n0 + row) * K + kt + sc;
      *(s8v*)&Ah[row][sc] = *(const s8v*)&Ahi[ga];
      *(s8v*)&Al[row][sc] = *(const s8v*)&Alo[ga];
      *(s8v*)&Bh[row][sc] = *(const s8v*)&Bhi[gb];
      *(s8v*)&Bl[row][sc] = *(const s8v*)&Blo[gb];
    }
    __syncthreads();
    const int fr = lane & 15, fc = (lane >> 4) * 8;
    s8v bh[4], bl[4];
#pragma unroll
    for (int j = 0; j < 4; j++) {
      bh[j] = *(const s8v*)&Bh[wc * 64 + j * 16 + fr][fc];
      bl[j] = *(const s8v*)&Bl[wc * 64 + j * 16 + fr][fc];
    }
#pragma unroll
    for (int i = 0; i < 4; i++) {
      s8v ah = *(const s8v*)&Ah[wr * 64 + i * 16 + fr][fc];
      s8v al = *(const s8v*)&Al[wr * 64 + i * 16 + fr][fc];
#pragma unroll
      for (int j = 0; j < 4; j++) {
        acc[i][j] = __builtin_amdgcn_mfma_f32_16x16x32_bf16(ah, bh[j], acc[i][j], 0, 0, 0);
        acc[i][j] = __builtin_amdgcn_mfma_f32_16x16x32_bf16(ah, bl[j], acc[i][j], 0, 0, 0);
        acc[i][j] = __builtin_amdgcn_mfma_f32_16x16x32_bf16(al, bh[j], acc[i][j], 0, 0, 0);
      }
    }
    __syncthreads();
  }
  // Epilogue. C/D layout (m89/m91): col = lane&15, row = (lane>>4)*4 + r.
#pragma unroll
  for (int j = 0; j < 4; j++) {
    int col = n0 + wc * 64 + j * 16 + (lane & 15);
    float bv = bias[col];
#pragma unroll
    for (int i = 0; i < 4; i++) {
#pragma unroll
      for (int r = 0; r < 4; r++) {
        int row = m0 + wr * 64 + i * 16 + (lane >> 4) * 4 + r;
        float v = acc[i][j][r] + bv;
        if (RELU) v = fmaxf(v, 0.f);
        size_t idx = (size_t)row * N + col;
        if (OUT_F32) Cf[idx] = v;
        if (OUT_SPLIT) {
          u16 hi, lo; f2bf_split(v, hi, lo);
          Chi[idx] = hi;
          Clo[idx] = lo;
        }
      }
    }
  }
}

// ---------------------------------------------------------------------------
// Attention: one block (128 thr) per (batch-elem, head). 78x78 scores, fp32.
// Reads fp32 qkv; writes o as hi/lo bf16 split. Ss has +1 col pad.
// ---------------------------------------------------------------------------
__global__ __launch_bounds__(128) void k_attn(const float* __restrict__ qkvf,
                                              u16* __restrict__ ohi, u16* __restrict__ olo) {
  __shared__ float Ks[78][68];   // 68-f32 stride: 16B-aligned rows, 2-way banks
  __shared__ float Vs[78][68];
  __shared__ float Ss[78][79];
  const int bl = blockIdx.x >> 2, h = blockIdx.x & 3;
  const int tid = threadIdx.x;
  const size_t rowbase = (size_t)bl * 78;
  for (int ci = tid; ci < 1248; ci += 128) {   // 78 rows * 16 float4 chunks
    int row = ci >> 4, c4 = (ci & 15) * 4;
    const float* kp = &qkvf[(rowbase + row) * 768 + 256 + h * 64 + c4];
    *(float4*)&Ks[row][c4] = *(const float4*)kp;
    *(float4*)&Vs[row][c4] = *(const float4*)(kp + 256);
  }
  __syncthreads();
  const int q = tid;
  if (q < 78) {
    float qv[64];
    const float* qp = &qkvf[(rowbase + q) * 768 + h * 64];
#pragma unroll
    for (int d4 = 0; d4 < 64; d4 += 4) {
      float4 t = *(const float4*)&qp[d4];
      qv[d4] = t.x; qv[d4 + 1] = t.y; qv[d4 + 2] = t.z; qv[d4 + 3] = t.w;
    }
    float mx = -1e30f;
    for (int k = 0; k < 78; k++) {
      float s = 0.f;
#pragma unroll
      for (int d = 0; d < 64; d++) s += qv[d] * Ks[k][d];
      s *= 0.125f;                      // 1/sqrt(64)
      Ss[q][k] = s;
      mx = fmaxf(mx, s);
    }
    float sum = 0.f;
    for (int k = 0; k < 78; k++) { float e = __expf(Ss[q][k] - mx); Ss[q][k] = e; sum += e; }
    float inv = 1.f / sum;
    float ov[64];
#pragma unroll
    for (int d = 0; d < 64; d++) ov[d] = 0.f;
    for (int k = 0; k < 78; k++) {
      float p = Ss[q][k];
#pragma unroll
      for (int d = 0; d < 64; d++) ov[d] += p * Vs[k][d];
    }
    size_t obase = (rowbase + q) * 256 + h * 64;
#pragma unroll
    for (int d8 = 0; d8 < 64; d8 += 8) {
      s8v whi, wlo;
#pragma unroll
      for (int j = 0; j < 8; j++) {
        u16 hi, lo; f2bf_split(ov[d8 + j] * inv, hi, lo);
        whi[j] = (short)hi; wlo[j] = (short)lo;
      }
      *(s8v*)&ohi[obase + d8] = whi;
      *(s8v*)&olo[obase + d8] = wlo;
    }
  }
}

// ---------------------------------------------------------------------------
// (opt add) + LayerNorm over D=256. 4 rows/block, one wave per row.
// Writes f32 + hi/lo bf16.
// ---------------------------------------------------------------------------
template <bool ADD>
__global__ __launch_bounds__(256) void k_addln(const float* __restrict__ x,
                                               const float* __restrict__ t,
                                               const float* __restrict__ g,
                                               const float* __restrict__ b,
                                               float* __restrict__ xo,
                                               u16* __restrict__ xhi, u16* __restrict__ xlo) {
  int row = blockIdx.x * 4 + (threadIdx.x >> 6);
  int lane = threadIdx.x & 63;
  const float* xr = x + (size_t)row * 256;
  float4 v = *(const float4*)&xr[lane * 4];
  if (ADD) {
    float4 tv = *(const float4*)&t[(size_t)row * 256 + lane * 4];
    v.x += tv.x; v.y += tv.y; v.z += tv.z; v.w += tv.w;
  }
  float s = v.x + v.y + v.z + v.w;
  float q = v.x * v.x + v.y * v.y + v.z * v.z + v.w * v.w;
#pragma unroll
  for (int off = 32; off; off >>= 1) { s += __shfl_down(s, off); q += __shfl_down(q, off); }
  s = __shfl(s, 0); q = __shfl(q, 0);
  float mean = s * (1.f / 256.f);
  float var = q * (1.f / 256.f) - mean * mean;
  float rstd = rsqrtf(var + 1e-5f);
  float4 gg = *(const float4*)&g[lane * 4];
  float4 bb = *(const float4*)&b[lane * 4];
  float o0 = (v.x - mean) * rstd * gg.x + bb.x;
  float o1 = (v.y - mean) * rstd * gg.y + bb.y;
  float o2 = (v.z - mean) * rstd * gg.z + bb.z;
  float o3 = (v.w - mean) * rstd * gg.w + bb.w;
  size_t base = (size_t)row * 256 + lane * 4;
  *(float4*)&xo[base] = make_float4(o0, o1, o2, o3);
  u16 h0, l0, h1, l1, h2, l2, h3, l3;
  f2bf_split(o0, h0, l0); f2bf_split(o1, h1, l1);
  f2bf_split(o2, h2, l2); f2bf_split(o3, h3, l3);
  u16x4 vh = { h0, h1, h2, h3 };
  u16x4 vl = { l0, l1, l2, l3 };
  *(u16x4*)&xhi[base] = vh;
  *(u16x4*)&xlo[base] = vl;
}

// Mean over 78 tokens -> out[b, d]
__global__ __launch_bounds__(256) void k_mean(const float* __restrict__ p2,
                                              float* __restrict__ out, int b0) {
  int bl = blockIdx.x, d = threadIdx.x;
  const float* base = p2 + (size_t)bl * 78 * 256 + d;
  float s = 0.f;
#pragma unroll 13
  for (int p = 0; p < 78; p++) s += base[(size_t)p * 256];
  out[(size_t)(b0 + bl) * 256 + d] = s * (1.f / 78.f);
}

__global__ __launch_bounds__(256) void k_zero(float* p, int n) {
  int i = blockIdx.x * 256 + threadIdx.x;
  if (i < n) p[i] = 0.f;
}

// ---------------------------------------------------------------------------
// HRM (fp32). concat order: [zL, zH, out] for l_net, [zH, zL] for h_net.
// baseL = L_b1 + zH@L_w1[256:512] + out@L_w1[512:768] (recomputed per period)
// ---------------------------------------------------------------------------
__global__ __launch_bounds__(256) void k_lbase(const float* __restrict__ zH,
                                               const float* __restrict__ out,
                                               const float* __restrict__ W1,
                                               const float* __restrict__ b1,
                                               float* __restrict__ baseL) {
  int r0 = blockIdx.x * 4, col = threadIdx.x;
  __shared__ float t[4][512];
#pragma unroll
  for (int i = 0; i < 4; i++) {
    t[i][col] = zH[(size_t)(r0 + i) * 256 + col];
    t[i][256 + col] = out[(size_t)(r0 + i) * 256 + col];
  }
  __syncthreads();
  float acc[4];
#pragma unroll
  for (int i = 0; i < 4; i++) acc[i] = b1[col];
  for (int k = 0; k < 512; k++) {
    float w = W1[(size_t)(256 + k) * 256 + col];
#pragma unroll
    for (int i = 0; i < 4; i++) acc[i] += t[i][k] * w;
  }
#pragma unroll
  for (int i = 0; i < 4; i++) baseL[(size_t)(r0 + i) * 256 + col] = acc[i];
}

DEV void row_ln_stats(float a2[4], int col, float (*redS)[4], float (*redQ)[4],
                      float mean[4], float rstd[4]) {
  int wid = col >> 6, lane = col & 63;
#pragma unroll
  for (int i = 0; i < 4; i++) {
    float s = a2[i], q = a2[i] * a2[i];
#pragma unroll
    for (int off = 32; off; off >>= 1) { s += __shfl_down(s, off); q += __shfl_down(q, off); }
    if (lane == 0) { redS[i][wid] = s; redQ[i][wid] = q; }
  }
  __syncthreads();
#pragma unroll
  for (int i = 0; i < 4; i++) {
    float s = redS[i][0] + redS[i][1] + redS[i][2] + redS[i][3];
    float q = redQ[i][0] + redQ[i][1] + redQ[i][2] + redQ[i][3];
    mean[i] = s * (1.f / 256.f);
    float var = q * (1.f / 256.f) - mean[i] * mean[i];
    rstd[i] = rsqrtf(var + 1e-5f);
  }
}

__global__ __launch_bounds__(256) void k_lstep(float* __restrict__ zL,
                                               const float* __restrict__ baseL,
                                               const float* __restrict__ W1,
                                               const float* __restrict__ W2,
                                               const float* __restrict__ b2,
                                               const float* __restrict__ g,
                                               const float* __restrict__ bb) {
  int r0 = blockIdx.x * 4, col = threadIdx.x;
  __shared__ float t[4][256];
  __shared__ float h1[4][256];
  __shared__ float redS[4][4], redQ[4][4];
#pragma unroll
  for (int i = 0; i < 4; i++) t[i][col] = zL[(size_t)(r0 + i) * 256 + col];
  __syncthreads();
  float acc[4];
#pragma unroll
  for (int i = 0; i < 4; i++) acc[i] = baseL[(size_t)(r0 + i) * 256 + col];
  for (int k = 0; k < 256; k++) {
    float w = W1[(size_t)k * 256 + col];
#pragma unroll
    for (int i = 0; i < 4; i++) acc[i] += t[i][k] * w;
  }
#pragma unroll
  for (int i = 0; i < 4; i++) h1[i][col] = fmaxf(acc[i], 0.f);
  __syncthreads();
  float a2[4];
#pragma unroll
  for (int i = 0; i < 4; i++) a2[i] = b2[col];
  for (int k = 0; k < 256; k++) {
    float w = W2[(size_t)k * 256 + col];
#pragma unroll
    for (int i = 0; i < 4; i++) a2[i] += h1[i][k] * w;
  }
#pragma unroll
  for (int i = 0; i < 4; i++) a2[i] = fmaxf(a2[i], 0.f);
  float mean[4], rstd[4];
  row_ln_stats(a2, col, redS, redQ, mean, rstd);
#pragma unroll
  for (int i = 0; i < 4; i++)
    zL[(size_t)(r0 + i) * 256 + col] = (a2[i] - mean[i]) * rstd[i] * g[col] + bb[col];
}

__global__ __launch_bounds__(256) void k_hstep(float* __restrict__ zH,
                                               const float* __restrict__ zL,
                                               const float* __restrict__ W1,
                                               const float* __restrict__ b1,
                                               const float* __restrict__ W2,
                                               const float* __restrict__ b2,
                                               const float* __restrict__ g,
                                               const float* __restrict__ bb) {
  int r0 = blockIdx.x * 4, col = threadIdx.x;
  __shared__ float t[4][512];
  __shared__ float h1[4][256];
  __shared__ float redS[4][4], redQ[4][4];
#pragma unroll
  for (int i = 0; i < 4; i++) {
    t[i][col] = zH[(size_t)(r0 + i) * 256 + col];
    t[i][256 + col] = zL[(size_t)(r0 + i) * 256 + col];
  }
  __syncthreads();
  float acc[4];
#pragma unroll
  for (int i = 0; i < 4; i++) acc[i] = b1[col];
  for (int k = 0; k < 512; k++) {
    float w = W1[(size_t)k * 256 + col];
#pragma unroll
    for (int i = 0; i < 4; i++) acc[i] += t[i][k] * w;
  }
#pragma unroll
  for (int i = 0; i < 4; i++) h1[i][col] = fmaxf(acc[i], 0.f);
  __syncthreads();
  float a2[4];
#pragma unroll
  for (int i = 0; i < 4; i++) a2[i] = b2[col];
  for (int k = 0; k < 256; k++) {
    float w = W2[(size_t)k * 256 + col];
#pragma unroll
    for (int i = 0; i < 4; i++) a2[i] += h1[i][k] * w;
  }
#pragma unroll
  for (int i = 0; i < 4; i++) a2[i] = fmaxf(a2[i], 0.f);
  float mean[4], rstd[4];
  row_ln_stats(a2, col, redS, redQ, mean, rstd);
#pragma unroll
  for (int i = 0; i < 4; i++)
    zH[(size_t)(r0 + i) * 256 + col] = (a2[i] - mean[i]) * rstd[i] * g[col] + bb[col];
}

// Final head: vh = LN(zH); y = relu(vh @ vw1 + vb1) @ vw2 + vb2  -> [1024,128]
__global__ __launch_bounds__(256) void k_vh(const float* __restrict__ zH,
                                            const float* __restrict__ g,
                                            const float* __restrict__ bb,
                                            const float* __restrict__ W1,
                                            const float* __restrict__ b1,
                                            const float* __restrict__ W2,
                                            const float* __restrict__ b2,
                                            float* __restrict__ out) {
  int r0 = blockIdx.x * 4, col = threadIdx.x;
  __shared__ float t[4][256];
  __shared__ float h1[4][256];
  __shared__ float redS[4][4], redQ[4][4];
  float v[4];
#pragma unroll
  for (int i = 0; i < 4; i++) v[i] = zH[(size_t)(r0 + i) * 256 + col];
  float mean[4], rstd[4];
  row_ln_stats(v, col, redS, redQ, mean, rstd);
#pragma unroll
  for (int i = 0; i < 4; i++) t[i][col] = (v[i] - mean[i]) * rstd[i] * g[col] + bb[col];
  __syncthreads();
  float acc[4];
#pragma unroll
  for (int i = 0; i < 4; i++) acc[i] = b1[col];
  for (int k = 0; k < 256; k++) {
    float w = W1[(size_t)k * 256 + col];
#pragma unroll
    for (int i = 0; i < 4; i++) acc[i] += t[i][k] * w;
  }
#pragma unroll
  for (int i = 0; i < 4; i++) h1[i][col] = fmaxf(acc[i], 0.f);
  __syncthreads();
  if (col < 128) {
    float a2[4];
#pragma unroll
    for (int i = 0; i < 4; i++) a2[i] = b2[col];
    for (int k = 0; k < 256; k++) {
      float w = W2[(size_t)k * 128 + col];
#pragma unroll
      for (int i = 0; i < 4; i++) a2[i] += h1[i][k] * w;
    }
#pragma unroll
    for (int i = 0; i < 4; i++) out[(size_t)(r0 + i) * 128 + col] = a2[i];
  }
}

// ---------------------------------------------------------------------------
extern "C" void kernel_launch(void* const* d_in, const int* in_sizes, int n_in,
                              void* d_out, int out_size, void* d_ws, size_t ws_size,
                              hipStream_t stream) {
  (void)in_sizes; (void)n_in; (void)out_size;
  const int* fen = (const int*)d_in[0];
  const int* uci = (const int*)d_in[1];
  const float* femb = (const float*)d_in[2];
  const float* uemb = (const float*)d_in[3];
  const float* pemb = (const float*)d_in[4];
  const float* wqkv = (const float*)d_in[5];
  const float* bqkv = (const float*)d_in[6];
  const float* wo_ = (const float*)d_in[7];
  const float* bo_ = (const float*)d_in[8];
  const float* ln1g = (const float*)d_in[9];
  const float* ln1b = (const float*)d_in[10];
  const float* w1_ = (const float*)d_in[11];
  const float* b1_ = (const float*)d_in[12];
  const float* w2_ = (const float*)d_in[13];
  const float* b2_ = (const float*)d_in[14];
  const float* ln2g = (const float*)d_in[15];
  const float* ln2b = (const float*)d_in[16];
  const float* postg = (const float*)d_in[17];
  const float* postb = (const float*)d_in[18];
  const float* pw1 = (const float*)d_in[19];
  const float* pb1 = (const float*)d_in[20];
  const float* pw2 = (const float*)d_in[21];
  const float* pb2 = (const float*)d_in[22];
  const float* Lw1 = (const float*)d_in[23];
  const float* Lb1 = (const float*)d_in[24];
  const float* Lw2 = (const float*)d_in[25];
  const float* Lb2 = (const float*)d_in[26];
  const float* Llng = (const float*)d_in[27];
  const float* Llnb = (const float*)d_in[28];
  const float* Hw1 = (const float*)d_in[29];
  const float* Hb1 = (const float*)d_in[30];
  const float* Hw2 = (const float*)d_in[31];
  const float* Hb2 = (const float*)d_in[32];
  const float* Hlng = (const float*)d_in[33];
  const float* Hlnb = (const float*)d_in[34];
  const float* vhg = (const float*)d_in[35];
  const float* vhb = (const float*)d_in[36];
  const float* vw1 = (const float*)d_in[37];
  const float* vb1 = (const float*)d_in[38];
  const float* vw2 = (const float*)d_in[39];
  const float* vb2 = (const float*)d_in[40];

  // ---- workspace carve-up ----
  char* p = (char*)d_ws;
  auto alloc = [&](size_t bytes) -> void* {
    void* r = (void*)p;
    p += (bytes + 255) & ~(size_t)255;
    return r;
  };
  float* outf = (float*)alloc(1024 * 256 * 4);       // pooled "out" [1024,256]
  float* baseL = (float*)alloc(1024 * 256 * 4);
  float* zLH = (float*)alloc(2 * 1024 * 256 * 4);
  float* zL = zLH;
  float* zH = zLH + 1024 * 256;
  u16* wqThi = (u16*)alloc((size_t)4 * 768 * 256 * 2);
  u16* wqTlo = (u16*)alloc((size_t)4 * 768 * 256 * 2);
  u16* woThi = (u16*)alloc((size_t)4 * 256 * 256 * 2);
  u16* woTlo = (u16*)alloc((size_t)4 * 256 * 256 * 2);
  u16* w1Thi = (u16*)alloc((size_t)4 * 2048 * 256 * 2);
  u16* w1Tlo = (u16*)alloc((size_t)4 * 2048 * 256 * 2);
  u16* w2Thi = (u16*)alloc((size_t)4 * 256 * 2048 * 2);
  u16* w2Tlo = (u16*)alloc((size_t)4 * 256 * 2048 * 2);
  u16* pw1Thi = (u16*)alloc((size_t)256 * 256 * 2);
  u16* pw1Tlo = (u16*)alloc((size_t)256 * 256 * 2);
  u16* pw2Thi = (u16*)alloc((size_t)256 * 256 * 2);
  u16* pw2Tlo = (u16*)alloc((size_t)256 * 256 * 2);

  size_t fixed = (size_t)(p - (char*)d_ws);
  // per-row chunk bytes: xf 1024 + tmp 1024 + xhi/xlo 1024 + qkvf 3072
  //                    + ohi/olo 1024 + hhi/hlo 8192 = 15360
  // NC=8 DELIBERATELY preferred: chunk working set ~200 MB = L3-resident
  // (r3 measured 10992 us at NC=8; r4's NC=1 spilled FFN hidden 654 MB to
  // HBM and regressed). Fall to 16 (smaller) if 8 doesn't fit.
  int NC = 16;
  for (int c : {8, 16, 4, 2, 1}) {
    size_t Mc_ = (size_t)(1024 / c) * 78;
    if (fixed + Mc_ * 15360 + (size_t)(1 << 20) <= ws_size) { NC = c; break; }
  }
  const int Bc = 1024 / NC;
  const size_t Mc = (size_t)Bc * 78;

  float* xf = (float*)alloc(Mc * 256 * 4);
  float* tmp = (float*)alloc(Mc * 256 * 4);
  u16* xhi = (u16*)alloc(Mc * 256 * 2);
  u16* xlo = (u16*)alloc(Mc * 256 * 2);
  float* qkvf = (float*)alloc(Mc * 768 * 4);
  u16* ohi = (u16*)alloc(Mc * 256 * 2);   // attn out; reused as pool1 out
  u16* olo = (u16*)alloc(Mc * 256 * 2);
  u16* hhi = (u16*)alloc(Mc * 2048 * 2);
  u16* hlo = (u16*)alloc(Mc * 2048 * 2);

  // ---- weight transpose+split (per call; inputs restored each launch) ----
  auto tr = [&](const float* W, u16* WThi, u16* WTlo, int K, int N) {
    k_transpose<<<dim3(K / 32, N / 32), 256, 0, stream>>>(W, WThi, WTlo, K, N);
  };
  for (int l = 0; l < 4; l++) {
    tr(wqkv + (size_t)l * 256 * 768, wqThi + (size_t)l * 768 * 256,
       wqTlo + (size_t)l * 768 * 256, 256, 768);
    tr(wo_ + (size_t)l * 256 * 256, woThi + (size_t)l * 256 * 256,
       woTlo + (size_t)l * 256 * 256, 256, 256);
    tr(w1_ + (size_t)l * 256 * 2048, w1Thi + (size_t)l * 2048 * 256,
       w1Tlo + (size_t)l * 2048 * 256, 256, 2048);
    tr(w2_ + (size_t)l * 2048 * 256, w2Thi + (size_t)l * 256 * 2048,
       w2Tlo + (size_t)l * 256 * 2048, 2048, 256);
  }
  tr(pw1, pw1Thi, pw1Tlo, 256, 256);
  tr(pw2, pw2Thi, pw2Tlo, 256, 256);

  // ---- transformer + pool, chunked over batch ----
  const int MT = (int)(Mc / 128);
  for (int ch = 0; ch < NC; ch++) {
    int b0 = ch * Bc;
    k_embed<<<(int)Mc, 256, 0, stream>>>(fen, uci, femb, uemb, pemb, xf, xhi, xlo, b0);
    for (int l = 0; l < 4; l++) {
      k_gemm<false, true, false><<<dim3(MT, 6), 256, 0, stream>>>(
          xhi, xlo, wqThi + (size_t)l * 768 * 256, wqTlo + (size_t)l * 768 * 256,
          bqkv + l * 768, qkvf, nullptr, nullptr, (int)Mc, 768, 256);
      k_attn<<<Bc * 4, 128, 0, stream>>>(qkvf, ohi, olo);
      k_gemm<false, true, false><<<dim3(MT, 2), 256, 0, stream>>>(
          ohi, olo, woThi + (size_t)l * 256 * 256, woTlo + (size_t)l * 256 * 256,
          bo_ + l * 256, tmp, nullptr, nullptr, (int)Mc, 256, 256);
      k_addln<true><<<(int)(Mc / 4), 256, 0, stream>>>(
          xf, tmp, ln1g + l * 256, ln1b + l * 256, xf, xhi, xlo);
      k_gemm<true, false, true><<<dim3(MT, 16), 256, 0, stream>>>(
          xhi, xlo, w1Thi + (size_t)l * 2048 * 256, w1Tlo + (size_t)l * 2048 * 256,
          b1_ + l * 2048, nullptr, hhi, hlo, (int)Mc, 2048, 256);
      k_gemm<false, true, false><<<dim3(MT, 2), 256, 0, stream>>>(
          hhi, hlo, w2Thi + (size_t)l * 256 * 2048, w2Tlo + (size_t)l * 256 * 2048,
          b2_ + l * 256, tmp, nullptr, nullptr, (int)Mc, 256, 2048);
      k_addln<true><<<(int)(Mc / 4), 256, 0, stream>>>(
          xf, tmp, ln2g + l * 256, ln2b + l * 256, xf, xhi, xlo);
    }
    k_addln<false><<<(int)(Mc / 4), 256, 0, stream>>>(xf, nullptr, postg, postb, xf, xhi, xlo);
    k_gemm<true, false, true><<<dim3(MT, 2), 256, 0, stream>>>(
        xhi, xlo, pw1Thi, pw1Tlo, pb1, nullptr, ohi, olo, (int)Mc, 256, 256);
    k_gemm<true, true, false><<<dim3(MT, 2), 256, 0, stream>>>(
        ohi, olo, pw2Thi, pw2Tlo, pb2, tmp, nullptr, nullptr, (int)Mc, 256, 256);
    k_mean<<<Bc, 256, 0, stream>>>(tmp, outf, b0);
  }

  // ---- HRM recurrence (fp32) ----
  k_zero<<<(2 * 1024 * 256) / 256, 256, 0, stream>>>(zLH, 2 * 1024 * 256);
  for (int st = 0; st < 64; st++) {
    if ((st & 7) == 0)
      k_lbase<<<256, 256, 0, stream>>>(zH, outf, Lw1, Lb1, baseL);
    k_lstep<<<256, 256, 0, stream>>>(zL, baseL, Lw1, Lw2, Lb2, Llng, Llnb);
    if ((st & 7) == 7)
      k_hstep<<<256, 256, 0, stream>>>(zH, zL, Hw1, Hb1, Hw2, Hb2, Hlng, Hlnb);
  }
  k_vh<<<256, 256, 0, stream>>>(zH, vhg, vhb, vw1, vb1, vw2, vb2, (float*)d_out);
}